// Round 6
// baseline (66.611 us; speedup 1.0000x reference)
//
#include <hip/hip_runtime.h>
#include <hip/hip_bf16.h>

// NeRF surrogate renderer, MI355X — round 6.
// Rounds 3-5 all ~65us: uniform weight loads INSIDE the sample-chunk j-loop
// serialize on K$/LDS latency at ~3 waves/SIMD. Fix: loop inversion — j is the
// OUTER loop (weights loaded once per j, prefetchable across unroll-4), samples
// held in packed v2f accumulators. 32 threads/ray (4 samples each) keeps accum
// pressure at 16 v2f -> high occupancy; width-32 log-scan combines segments.

typedef float v2f __attribute__((ext_vector_type(2)));
typedef float v4f __attribute__((ext_vector_type(4)));

__device__ __forceinline__ float fast_rcp(float x) { return __builtin_amdgcn_rcpf(x); }

__device__ __forceinline__ float softplus_f(float x) {
    float e = __expf(-fabsf(x));
    return fmaxf(x, 0.0f) + __logf(1.0f + e);
}
__device__ __forceinline__ float sigmoid_f(float x) {
    return fast_rcp(1.0f + __expf(-x));
}

__device__ __forceinline__ v2f pkfma(v2f a, v2f b, v2f c) {
    return __builtin_elementwise_fma(a, b, c);   // v_pk_fma_f32
}
__device__ __forceinline__ v2f relu2(v2f a) {
    const v2f z = {0.0f, 0.0f};
    return __builtin_elementwise_max(a, z);
}
__device__ __forceinline__ v2f clamp11(v2f a) {
    const v2f lo = {-1.0f, -1.0f}, hi = {1.0f, 1.0f};
    return __builtin_elementwise_min(__builtin_elementwise_max(a, lo), hi);
}
#define SHV(q, i, j) __builtin_shufflevector((q), (q), (i), (j))

// ---- prep: pack weights into d_ws as 32 j-structs of 16 duplicated pairs ----
__global__ __launch_bounds__(256)
void nerf_prep_kernel(const float* __restrict__ W1, const float* __restrict__ b1,
                      const float* __restrict__ Wsig, const float* __restrict__ Wsig_d,
                      const float* __restrict__ Wc1, const float* __restrict__ Wc2,
                      const float* __restrict__ Wc2_d, float* __restrict__ ws)
{
    int q = threadIdx.x;
#pragma unroll
    for (int k = 0; k < 2; ++k, q += 256) {
        const int j = q >> 4, p = q & 15;
        float v;
        switch (p) {
            case 0:  v = W1[j];        break;
            case 1:  v = W1[32 + j];   break;
            case 2:  v = W1[64 + j];   break;
            case 3:  v = b1[j];        break;
            case 4:  v = Wsig[j];      break;
            case 5:  v = Wsig_d[j];    break;
            case 6:  v = Wc1[j];       break;
            case 7:  v = Wc1[32 + j];  break;
            case 8:  v = Wc1[64 + j];  break;
            case 9:  v = Wc2[j*3 + 0]; break;
            case 10: v = Wc2[j*3 + 1]; break;
            case 11: v = Wc2[j*3 + 2]; break;
            case 12: v = Wc2_d[j*3 + 0]; break;
            case 13: v = Wc2_d[j*3 + 1]; break;
            case 14: v = Wc2_d[j*3 + 2]; break;
            default: v = 0.0f; break;
        }
        ws[q*2 + 0] = v;
        ws[q*2 + 1] = v;
    }
}

// ---- main: 32 threads/ray (4 samples each), 8 rays per 256-thr block ----
__global__ __launch_bounds__(256, 5)
void nerf_render_kernel(const float* __restrict__ rays_o,
                        const float* __restrict__ rays_d,
                        const float* __restrict__ Wc1,
                        const float* __restrict__ bc1,
                        const float* __restrict__ wsm,
                        const int*   __restrict__ num_steps,
                        float* __restrict__ out,
                        int N)
{
    __shared__ v2f dc2[8 * 33];   // [rayLocal][j] duplicated pairs, stride 33

    const int tid  = threadIdx.x;
    const int rayL = tid >> 5;          // 0..7
    const int seg  = tid & 31;          // 0..31
    const int ray  = blockIdx.x * 8 + rayL;
    const int rayc = (ray < N) ? ray : (N - 1);
    const int T = num_steps[0];

    const float ox = rays_o[rayc*3 + 0], oy = rays_o[rayc*3 + 1], oz = rays_o[rayc*3 + 2];
    const float rdx = rays_d[rayc*3 + 0], rdy = rays_d[rayc*3 + 1], rdz = rays_d[rayc*3 + 2];
    const float rn = rsqrtf(rdx*rdx + rdy*rdy + rdz*rdz);
    const float dx = rdx * rn, dy = rdy * rn, dz = rdz * rn;

    // per-ray dir preactivation: one unit per thread (j = seg)
    {
        const int j = seg;
        const float v = fmaf(dx, Wc1[96 + j], fmaf(dy, Wc1[128 + j], fmaf(dz, Wc1[160 + j], bc1[j])));
        dc2[rayL*33 + j] = (v2f){v, v};
    }
    __syncthreads();
    if (ray >= N) return;

    // AABB slab test, box = [-1,1]^3
    const float ix = 1.0f / dx, iy = 1.0f / dy, iz = 1.0f / dz;
    const float t1x = (-1.0f - ox) * ix, t2x = (1.0f - ox) * ix;
    const float t1y = (-1.0f - oy) * iy, t2y = (1.0f - oy) * iy;
    const float t1z = (-1.0f - oz) * iz, t2z = (1.0f - oz) * iz;
    float nearv = fmaxf(fmaxf(fminf(t1x, t2x), fminf(t1y, t2y)), fminf(t1z, t2z));
    float farv  = fminf(fminf(fmaxf(t1x, t2x), fmaxf(t1y, t2y)), fmaxf(t1z, t2z));
    nearv = fmaxf(nearv, 0.2f);
    farv  = fmaxf(farv, nearv + 1e-6f);

    const float span    = farv - nearv;
    const float stepz   = (T > 1) ? span / (float)(T - 1) : 0.0f;
    const float inv_tm1 = (T > 1) ? 1.0f / (float)(T - 1) : 0.0f;
    const float last_dt = span / (float)T;

    const v2f dxp = {dx, dx}, dyp = {dy, dy}, dzp = {dz, dz};
    const v2f oxp = {ox, ox}, oyp = {oy, oy}, ozp = {oz, oz};

    const int Sper = (T + 31) >> 5;     // 4 for T=128
    const int s0 = seg * Sper;
    int cnt = T - s0;
    cnt = (cnt < 0) ? 0 : ((cnt > Sper) ? Sper : cnt);

    float iA0 = 0.f, iA1 = 0.f, iA2 = 0.f, dAc = 0.f, wsA = 0.f, TAx = 1.0f;
    float iD0 = 0.f, iD1 = 0.f, iD2 = 0.f, dDc = 0.f, wsD = 0.f, TDx = 1.0f;

    const v4f* wv = (const v4f*)wsm;
    const v2f* dcp_base = dc2 + rayL*33;

    for (int cs = 0; cs < cnt; cs += 4) {
        const float tb = (float)(s0 + cs);
        const v2f zv0 = {fmaf(stepz, tb,        nearv), fmaf(stepz, tb + 1.0f, nearv)};
        const v2f zv1 = {fmaf(stepz, tb + 2.0f, nearv), fmaf(stepz, tb + 3.0f, nearv)};
        const v2f X0 = clamp11(pkfma(dxp, zv0, oxp));
        const v2f Y0 = clamp11(pkfma(dyp, zv0, oyp));
        const v2f Z0 = clamp11(pkfma(dzp, zv0, ozp));
        const v2f X1 = clamp11(pkfma(dxp, zv1, oxp));
        const v2f Y1 = clamp11(pkfma(dyp, zv1, oyp));
        const v2f Z1 = clamp11(pkfma(dzp, zv1, ozp));

        v2f sA0v = {0,0}, sD0v = {0,0}, c0A0 = {0,0}, c1A0 = {0,0}, c2A0 = {0,0},
            c0D0 = {0,0}, c1D0 = {0,0}, c2D0 = {0,0};
        v2f sA1v = {0,0}, sD1v = {0,0}, c0A1 = {0,0}, c1A1 = {0,0}, c2A1 = {0,0},
            c0D1 = {0,0}, c1D1 = {0,0}, c2D1 = {0,0};

        // j OUTER over hidden units: weights loaded once per j (uniform ->
        // s_load), 32 packed FMAs of register-only compute per j hide the
        // next iteration's prefetch (unroll 4).
#pragma unroll 4
        for (int j = 0; j < 32; ++j) {
            const v4f q0 = wv[j*8 + 0];
            const v4f q1 = wv[j*8 + 1];
            const v4f q2 = wv[j*8 + 2];
            const v4f q3 = wv[j*8 + 3];
            const v4f q4 = wv[j*8 + 4];
            const v4f q5 = wv[j*8 + 5];
            const v4f q6 = wv[j*8 + 6];
            const v4f q7 = wv[j*8 + 7];
            const v2f dcp = dcp_base[j];

            const v2f w1x = SHV(q0, 0, 1), w1y = SHV(q0, 2, 3);
            const v2f w1z = SHV(q1, 0, 1), b1p = SHV(q1, 2, 3);
            const v2f wsa = SHV(q2, 0, 1), wsd = SHV(q2, 2, 3);
            const v2f wcx = SHV(q3, 0, 1), wcy = SHV(q3, 2, 3);
            const v2f wcz = SHV(q4, 0, 1), wa0 = SHV(q4, 2, 3);
            const v2f wa1 = SHV(q5, 0, 1), wa2 = SHV(q5, 2, 3);
            const v2f wd0 = SHV(q6, 0, 1), wd1 = SHV(q6, 2, 3);
            const v2f wd2 = SHV(q7, 0, 1);

            v2f h0 = relu2(pkfma(X0, w1x, pkfma(Y0, w1y, pkfma(Z0, w1z, b1p))));
            v2f h1 = relu2(pkfma(X1, w1x, pkfma(Y1, w1y, pkfma(Z1, w1z, b1p))));
            sA0v = pkfma(h0, wsa, sA0v);  sD0v = pkfma(h0, wsd, sD0v);
            sA1v = pkfma(h1, wsa, sA1v);  sD1v = pkfma(h1, wsd, sD1v);

            v2f g0 = relu2(pkfma(X0, wcx, pkfma(Y0, wcy, pkfma(Z0, wcz, dcp))));
            v2f g1 = relu2(pkfma(X1, wcx, pkfma(Y1, wcy, pkfma(Z1, wcz, dcp))));
            c0A0 = pkfma(g0, wa0, c0A0);  c1A0 = pkfma(g0, wa1, c1A0);  c2A0 = pkfma(g0, wa2, c2A0);
            c0D0 = pkfma(g0, wd0, c0D0);  c1D0 = pkfma(g0, wd1, c1D0);  c2D0 = pkfma(g0, wd2, c2D0);
            c0A1 = pkfma(g1, wa0, c0A1);  c1A1 = pkfma(g1, wa1, c1A1);  c2A1 = pkfma(g1, wa2, c2A1);
            c0D1 = pkfma(g1, wd0, c0D1);  c1D1 = pkfma(g1, wd1, c1D1);  c2D1 = pkfma(g1, wd2, c2D1);
        }

#define COMPOSITE(I, SA, SD, R0A, R1A, R2A, R0D, R1D, R2D)                         \
        do {                                                                        \
            const int li = cs + (I);                                                \
            if (li < cnt) {                                                         \
                const int t = s0 + li;                                              \
                const float sigA = softplus_f(SA);                                  \
                const float sigD = softplus_f(SD);                                  \
                const float delta = (t < T - 1) ? stepz : last_dt;                  \
                const float z01 = fminf(fmaxf((float)t * inv_tm1, 0.0f), 1.0f);     \
                const float aA = 1.0f - __expf(-delta * sigA);                      \
                const float wA = aA * TAx;                                          \
                TAx = TAx * (1.0f - aA + 1e-15f);                                   \
                iA0 = fmaf(wA, sigmoid_f(R0A), iA0);                                \
                iA1 = fmaf(wA, sigmoid_f(R1A), iA1);                                \
                iA2 = fmaf(wA, sigmoid_f(R2A), iA2);                                \
                dAc = fmaf(wA, z01, dAc);                                           \
                wsA += wA;                                                          \
                const float aD = 1.0f - __expf(-delta * sigD);                      \
                const float wD = aD * TDx;                                          \
                TDx = TDx * (1.0f - aD + 1e-15f);                                   \
                iD0 = fmaf(wD, sigmoid_f(R0D), iD0);                                \
                iD1 = fmaf(wD, sigmoid_f(R1D), iD1);                                \
                iD2 = fmaf(wD, sigmoid_f(R2D), iD2);                                \
                dDc = fmaf(wD, z01, dDc);                                           \
                wsD += wD;                                                          \
            }                                                                       \
        } while (0)

        COMPOSITE(0, sA0v.x, sD0v.x, c0A0.x, c1A0.x, c2A0.x, c0D0.x, c1D0.x, c2D0.x);
        COMPOSITE(1, sA0v.y, sD0v.y, c0A0.y, c1A0.y, c2A0.y, c0D0.y, c1D0.y, c2D0.y);
        COMPOSITE(2, sA1v.x, sD1v.x, c0A1.x, c1A1.x, c2A1.x, c0D1.x, c1D1.x, c2D1.x);
        COMPOSITE(3, sA1v.y, sD1v.y, c0A1.y, c1A1.y, c2A1.y, c0D1.y, c1D1.y, c2D1.y);
#undef COMPOSITE
    }

    // combine 32 segments: exclusive prefix product of transmittance (log-scan),
    // scale each segment's contributions, butterfly-sum over the 32 lanes.
    float scanA = TAx, scanD = TDx;
#pragma unroll
    for (int off = 1; off < 32; off <<= 1) {
        const float tA_ = __shfl_up(scanA, off, 32);
        const float tD_ = __shfl_up(scanD, off, 32);
        if (seg >= off) { scanA *= tA_; scanD *= tD_; }
    }
    float exA = __shfl_up(scanA, 1, 32);
    float exD = __shfl_up(scanD, 1, 32);
    if (seg == 0) { exA = 1.0f; exD = 1.0f; }

    iA0 *= exA; iA1 *= exA; iA2 *= exA; dAc *= exA; wsA *= exA;
    iD0 *= exD; iD1 *= exD; iD2 *= exD; dDc *= exD; wsD *= exD;

#pragma unroll
    for (int mask = 1; mask < 32; mask <<= 1) {
        iA0 += __shfl_xor(iA0, mask, 32);
        iA1 += __shfl_xor(iA1, mask, 32);
        iA2 += __shfl_xor(iA2, mask, 32);
        dAc += __shfl_xor(dAc, mask, 32);
        wsA += __shfl_xor(wsA, mask, 32);
        iD0 += __shfl_xor(iD0, mask, 32);
        iD1 += __shfl_xor(iD1, mask, 32);
        iD2 += __shfl_xor(iD2, mask, 32);
        dDc += __shfl_xor(dDc, mask, 32);
        wsD += __shfl_xor(wsD, mask, 32);
    }

    if (seg == 0) {
        const float bgA = 1.0f - wsA;
        const float bgD = 1.0f - wsD;
        float* o = out + (size_t)ray * 9;
        o[0] = iA0 + bgA;
        o[1] = iA1 + bgA;
        o[2] = iA2 + bgA;
        o[3] = dAc;
        o[4] = wsA;
        o[5] = iD0 + bgD;
        o[6] = iD1 + bgD;
        o[7] = iD2 + bgD;
        o[8] = dDc;
    }
}

extern "C" void kernel_launch(void* const* d_in, const int* in_sizes, int n_in,
                              void* d_out, int out_size, void* d_ws, size_t ws_size,
                              hipStream_t stream) {
    const float* rays_o = (const float*)d_in[0];
    const float* rays_d = (const float*)d_in[1];
    const float* W1     = (const float*)d_in[2];
    const float* b1     = (const float*)d_in[3];
    const float* Wsig   = (const float*)d_in[4];
    const float* Wsig_d = (const float*)d_in[5];
    const float* Wc1    = (const float*)d_in[6];
    const float* bc1    = (const float*)d_in[7];
    const float* Wc2    = (const float*)d_in[8];
    const float* Wc2_d  = (const float*)d_in[9];
    const int* num_steps = (const int*)d_in[10];

    const int N = in_sizes[0] / 3;
    float* out = (float*)d_out;
    float* ws  = (float*)d_ws;   // needs 4 KB

    hipLaunchKernelGGL(nerf_prep_kernel, dim3(1), dim3(256), 0, stream,
                       W1, b1, Wsig, Wsig_d, Wc1, Wc2, Wc2_d, ws);

    const int blocks = (N + 7) / 8;   // 8 rays per 256-thread block
    hipLaunchKernelGGL(nerf_render_kernel, dim3(blocks), dim3(256), 0, stream,
                       rays_o, rays_d, Wc1, bc1, ws, num_steps, out, N);
}